// Round 5
// baseline (646.339 us; speedup 1.0000x reference)
//
#include <hip/hip_runtime.h>
#include <hip/hip_fp16.h>

#define BATCH 32
#define H 1024
#define W 1024
#define NPIX (H * W)       // 1048576 per sample
#define ITERS 10
#define SROWS 8            // rows per sub-strip (per 128-thread group)
#define BROWS 16           // rows per block (2 sub-strips)
#define STRIPS (H / BROWS) // 64

typedef _Float16 half8_t __attribute__((ext_vector_type(8)));

// Per-(iteration, batch) reduction state.
struct Stats {
    unsigned maxbits[ITERS][BATCH];  // fp32 bits; all values >= 0 so uint order == float order
    unsigned minbits[ITERS][BATCH];
    double   sum[ITERS][BATCH];
};

__global__ void init_stats(Stats* st) {
    int i = blockIdx.x * blockDim.x + threadIdx.x;
    if (i < ITERS * BATCH) {
        (&st->maxbits[0][0])[i] = 0u;           // erosion >= 0 everywhere
        (&st->minbits[0][0])[i] = 0x7f800000u;  // +inf
        (&st->sum[0][0])[i]     = 0.0;
    }
}

__device__ __forceinline__ float bound1(const float* __restrict__ pred,
                                        const int* __restrict__ tgt, size_t off) {
    float d = pred[off] - (tgt[off] == 0 ? 1.f : 0.f);
    return d * d;
}

// Load 8 px of row r for this thread (f[0..8)), plus left/right neighbor
// scalars L,R obtained via intra-wave shuffles of the register values.
// Wave-boundary lanes (cross-wave neighbor) do one predicated scalar load;
// image-edge lanes get 0. OOB rows produce all-zeros (SAME zero padding of
// the normalized field).
// MODE 0: values = (pred - (target==0))^2; MODE 1: normalized fp16 field.
template <int MODE>
__device__ __forceinline__ void row_load8(
    const float* __restrict__ pred, const int* __restrict__ target,
    const _Float16* __restrict__ in, size_t base, int r, int lane128,
    float emin, float invd, float f[8], float& L, float& R)
{
    const int  col = lane128 * 8;
    const bool inb = (r >= 0) && (r < H);
    size_t off = base + (size_t)r * W + col;
    if (inb) {
        if (MODE == 0) {
            float4 p0 = *(const float4*)(pred + off);
            float4 p1 = *(const float4*)(pred + off + 4);
            int4   t0 = *(const int4*)(target + off);
            int4   t1 = *(const int4*)(target + off + 4);
            float d;
            d = p0.x - (t0.x == 0 ? 1.f : 0.f); f[0] = d * d;
            d = p0.y - (t0.y == 0 ? 1.f : 0.f); f[1] = d * d;
            d = p0.z - (t0.z == 0 ? 1.f : 0.f); f[2] = d * d;
            d = p0.w - (t0.w == 0 ? 1.f : 0.f); f[3] = d * d;
            d = p1.x - (t1.x == 0 ? 1.f : 0.f); f[4] = d * d;
            d = p1.y - (t1.y == 0 ? 1.f : 0.f); f[5] = d * d;
            d = p1.z - (t1.z == 0 ? 1.f : 0.f); f[6] = d * d;
            d = p1.w - (t1.w == 0 ? 1.f : 0.f); f[7] = d * d;
        } else {
            half8_t x = *(const half8_t*)(in + off);
            #pragma unroll
            for (int j = 0; j < 8; ++j)
                f[j] = ((float)x[j] - emin) * invd;
        }
    } else {
        #pragma unroll
        for (int j = 0; j < 8; ++j) f[j] = 0.f;
    }

    // Whole wave executes these uniformly (each wave is fully inside one
    // sub-strip, same r for all its lanes).
    L = __shfl_up(f[7], 1, 64);
    R = __shfl_down(f[0], 1, 64);

    const int wl = lane128 & 63;
    if (!inb) { L = 0.f; R = 0.f; return; }
    if (lane128 == 0) {
        L = 0.f;                               // image left edge
    } else if (wl == 0) {                      // lane128 == 64: cross-wave
        size_t o = off - 1;
        L = (MODE == 0) ? bound1(pred, target, o)
                        : ((float)in[o] - emin) * invd;
    }
    if (lane128 == 127) {
        R = 0.f;                               // image right edge
    } else if (wl == 63) {                     // lane128 == 63: cross-wave
        size_t o = off + 8;
        R = (MODE == 0) ? bound1(pred, target, o)
                        : ((float)in[o] - emin) * invd;
    }
}

// One block = 16-row strip of one image; threads 0-127 handle rows
// [r0, r0+8), threads 128-255 handle [r0+8, r0+16). Each thread covers
// 8 px; sliding register window prev/cur/nxt (each row loaded once).
// Stats computed on fp32 values BEFORE fp16 rounding.
template <int MODE, int STORE>
__global__ __launch_bounds__(256) void erode_strip(
    const float* __restrict__ pred, const int* __restrict__ target,
    const _Float16* __restrict__ in, _Float16* __restrict__ out,
    Stats* __restrict__ st, int iter)
{
    const int blk = blockIdx.x;
    const int b   = blk >> 6;            // / STRIPS
    const int s   = blk & (STRIPS - 1);
    const int tid = threadIdx.x;
    const int sub     = tid >> 7;        // 0 or 1
    const int lane128 = tid & 127;
    const int r0  = s * BROWS + sub * SROWS;
    const int col = lane128 * 8;
    const size_t base = (size_t)b * NPIX;

    float emin = 0.f, invd = 1.f;
    if (MODE == 1) {
        float emax = __uint_as_float(st->maxbits[iter - 1][b]);
        float emn  = __uint_as_float(st->minbits[iter - 1][b]);
        float denom = emax - emn;
        if (denom != 0.f) { emin = emn; invd = 1.f / denom; }
        // else: identity -> erosion kept raw, matching reference
    }

    float prev[8], cur[8], nxt[8];
    float Lp, Rp, Lc, Rc, Ln, Rn;
    row_load8<MODE>(pred, target, in, base, r0 - 1, lane128, emin, invd, prev, Lp, Rp);
    row_load8<MODE>(pred, target, in, base, r0,     lane128, emin, invd, cur,  Lc, Rc);

    float  m  = 0.f;        // erosion >= 0
    float  mn = __builtin_inf();
    double sum = 0.0;

    #pragma unroll 2
    for (int i = 0; i < SROWS; ++i) {
        const int r = r0 + i;
        row_load8<MODE>(pred, target, in, base, r + 1, lane128, emin, invd, nxt, Ln, Rn);

        // dilation = 0.2*(c + l + r + up + dn); erosion = relu(d - 0.5)
        float e[8];
        #pragma unroll
        for (int j = 0; j < 8; ++j) {
            float lf = (j == 0) ? Lc : cur[j - 1];
            float rf = (j == 7) ? Rc : cur[j + 1];
            e[j] = fmaxf(0.2f * (cur[j] + lf + rf + prev[j] + nxt[j]) - 0.5f, 0.f);
        }

        if (STORE) {
            half8_t o;
            #pragma unroll
            for (int j = 0; j < 8; ++j) o[j] = (_Float16)e[j];
            *(half8_t*)(out + base + (size_t)r * W + col) = o;
        }

        float rm = fmaxf(fmaxf(fmaxf(e[0], e[1]), fmaxf(e[2], e[3])),
                         fmaxf(fmaxf(e[4], e[5]), fmaxf(e[6], e[7])));
        float rn = fminf(fminf(fminf(e[0], e[1]), fminf(e[2], e[3])),
                         fminf(fminf(e[4], e[5]), fminf(e[6], e[7])));
        float rs = ((e[0] + e[1]) + (e[2] + e[3])) + ((e[4] + e[5]) + (e[6] + e[7]));
        m   = fmaxf(m, rm);
        mn  = fminf(mn, rn);
        sum += (double)rs;

        #pragma unroll
        for (int j = 0; j < 8; ++j) { prev[j] = cur[j]; cur[j] = nxt[j]; }
        Lc = Ln; Rc = Rn;
    }

    // Block reduction: max / min / sum(double), then one atomic set per block.
    #pragma unroll
    for (int off = 32; off > 0; off >>= 1) {
        m   = fmaxf(m,  __shfl_down(m,  off, 64));
        mn  = fminf(mn, __shfl_down(mn, off, 64));
        sum += __shfl_down(sum, off, 64);
    }
    __shared__ float  smax[4];
    __shared__ float  smin[4];
    __shared__ double ssum[4];
    int lane = tid & 63, wave = tid >> 6;
    if (lane == 0) { smax[wave] = m; smin[wave] = mn; ssum[wave] = sum; }
    __syncthreads();
    if (tid == 0) {
        m   = fmaxf(fmaxf(smax[0], smax[1]), fmaxf(smax[2], smax[3]));
        mn  = fminf(fminf(smin[0], smin[1]), fminf(smin[2], smin[3]));
        sum = ssum[0] + ssum[1] + ssum[2] + ssum[3];
        atomicMax(&st->maxbits[iter][b], __float_as_uint(m));
        atomicMin(&st->minbits[iter][b], __float_as_uint(mn));
        atomicAdd(&st->sum[iter][b], sum);
    }
}

// loss = (1/(B*N)) * sum_k (k+1)^2 * [ (sum_raw - N*emin)/denom  if denom != 0 else sum_raw ]
__global__ void finalize(const Stats* __restrict__ st, float* __restrict__ out) {
    if (threadIdx.x == 0 && blockIdx.x == 0) {
        double total = 0.0;
        for (int k = 0; k < ITERS; ++k) {
            double w = (double)((k + 1) * (k + 1));
            for (int b = 0; b < BATCH; ++b) {
                float emax  = __uint_as_float(st->maxbits[k][b]);
                float emn   = __uint_as_float(st->minbits[k][b]);
                float denom = emax - emn;
                double s = st->sum[k][b];
                double sn;
                if (denom != 0.f)
                    sn = (s - (double)NPIX * (double)emn) / (double)denom;
                else
                    sn = s;
                total += w * sn;
            }
        }
        out[0] = (float)(total / ((double)BATCH * (double)NPIX));
    }
}

extern "C" void kernel_launch(void* const* d_in, const int* in_sizes, int n_in,
                              void* d_out, int out_size, void* d_ws, size_t ws_size,
                              hipStream_t stream) {
    (void)in_sizes; (void)n_in; (void)out_size;
    const float* pred   = (const float*)d_in[0];
    const int*   target = (const int*)d_in[1];

    const size_t fieldBytes = (size_t)BATCH * NPIX * sizeof(_Float16);  // 64 MB
    char* ws = (char*)d_ws;
    _Float16* bufA;
    _Float16* bufB;
    Stats* st;
    if (ws_size >= 2 * fieldBytes + sizeof(Stats)) {
        bufA = (_Float16*)ws;
        bufB = (_Float16*)(ws + fieldBytes);
        st   = (Stats*)(ws + 2 * fieldBytes);
    } else {
        // target is dead after iteration 0 (128 MB int32 holds the 64 MB fp16
        // field); harness restores d_in before every launch.
        bufA = (_Float16*)ws;
        bufB = (_Float16*)d_in[1];
        st   = (Stats*)(ws + fieldBytes);
    }

    init_stats<<<1, 320, 0, stream>>>(st);

    dim3 grid(BATCH * STRIPS), block(256);
    erode_strip<0, 1><<<grid, block, 0, stream>>>(pred, target, nullptr, bufA, st, 0);

    _Float16* src = bufA;
    _Float16* dst = bufB;
    for (int k = 1; k < ITERS; ++k) {
        if (k == ITERS - 1)
            erode_strip<1, 0><<<grid, block, 0, stream>>>(nullptr, nullptr, src, dst, st, k);
        else
            erode_strip<1, 1><<<grid, block, 0, stream>>>(nullptr, nullptr, src, dst, st, k);
        _Float16* t = src; src = dst; dst = t;
    }

    finalize<<<1, 64, 0, stream>>>(st, (float*)d_out);
}